// Round 17
// baseline (99.679 us; speedup 1.0000x reference)
//
#include <hip/hip_runtime.h>
#include <stdint.h>

// Problem constants (fixed by reference)
#define NB 32    // batch
#define NC 64    // input channels
#define NH 64
#define NW 64
#define NO 512   // output channels
#define ND 256   // dictionary atoms

typedef __bf16 bf16x8 __attribute__((ext_vector_type(8)));
typedef short  s16x8  __attribute__((ext_vector_type(8)));
typedef float  f32x4  __attribute__((ext_vector_type(4)));
typedef uint32_t u32x2 __attribute__((ext_vector_type(2)));

__device__ __forceinline__ uint16_t f2bf(float f) {
  uint32_t u = __builtin_bit_cast(uint32_t, f);
  u += 0x7fffu + ((u >> 16) & 1u);   // round-to-nearest-even
  return (uint16_t)(u >> 16);
}
__device__ __forceinline__ uint32_t pk2(float a, float b) {
  return (uint32_t)f2bf(a) | ((uint32_t)f2bf(b) << 16);
}
__device__ __forceinline__ float ubf_lo(uint32_t u) {
  return __builtin_bit_cast(float, u << 16);
}
__device__ __forceinline__ float ubf_hi(uint32_t u) {
  return __builtin_bit_cast(float, u & 0xffff0000u);
}

// async global->LDS, 16B per lane. LDS dest = wave-uniform base + lane*16.
__device__ __forceinline__ void gld16(const uint16_t* g, uint16_t* l) {
  __builtin_amdgcn_global_load_lds(
      (const __attribute__((address_space(1))) void*)(g),
      (__attribute__((address_space(3))) void*)(l), 16, 0, 0);
}

// ---------------- kernel 1: Wd build only (tiny, ~3 us) ------------------
// Wd[p][d][c] = dict[d][c][p] bf16, pre-swizzled:
//   Wd[((p*ND + d)*8 + ((c>>3) ^ (d&7)))*8 + (c&7)]
__global__ void k_prep_wd(const float* __restrict__ dict,
                          uint16_t*    __restrict__ Wd) {
  const int d = blockIdx.x;
  const int t = threadIdx.x;            // 256
#pragma unroll
  for (int j = 0; j < 3; ++j) {
    const int id = t + j * 256;
    if (id < 576) {
      const int c = id & 63, p = id >> 6;
      const int sl = ((p * ND + d) * 8 + ((c >> 3) ^ (d & 7))) * 8 + (c & 7);
      Wd[sl] = f2bf(dict[d * 576 + c * 9 + p]);
    }
  }
}

// ---------------- kernel 2: fused transpose + dict-conv + combine --------
// 512 blocks, 512 thr (8 waves). Block = (b, h-quad): 256 pix.
// PHASE 0 (new): transpose own 6 x-rows NCHW fp32 -> swizzled bf16 xs
//   directly (fp32 tile overlaid on the as region; 2 rows per barrier
//   pair). Eliminates the xh intermediate + serial prep kernel.
// PHASE 1 (verbatim R16): S[256 d][256 pix] = conv(x, dict) via MFMA;
//   as = dw-group [3 taps][256 d] (96 KB) restaged 2x.
// S -> LDS bf16 (128 KB overlay, XOR-swizzled rows).
// PHASE 2 (verbatim R16): out[o,pix] = sum_4 coef*S[idx] + bias,
//   wave-uniform-row ds_read_b64 gathers, f32x4 nt stores.
__global__ __launch_bounds__(512, 2) void k_conv(
    const float*    __restrict__ x,    // [NB][64][64][64] fp32 NCHW
    const uint16_t* __restrict__ Wd,   // [9][256][64] bf16, pre-swizzled
    const float*    __restrict__ coef, // [512][4]
    const int*      __restrict__ idx,  // [512][4], values in [0,256)
    const float*    __restrict__ bias, // [512]
    float*          __restrict__ out) {
  __shared__ __align__(16) uint16_t smem[74496];  // 148,992 B
  uint16_t* xs  = smem;            // [6][66][64] = 25,344 elems (50,688 B)
  uint16_t* asw = smem + 25344;    // [3][256][64] = 49,152 elems (98,304 B)
  uint8_t*  Sb  = (uint8_t*)smem;  // S overlay: 256 rows x 512 B = 128 KB

  const int t = threadIdx.x;
  const int lane = t & 63;
  const int wid  = t >> 6;      // 0..7
  // XCD-chunked: XCD k gets 64 consecutive s (4 b's, L2-resident slice)
  const int flat = blockIdx.x;                 // 512 blocks
  const int s    = (flat & 7) * 64 + (flat >> 3);
  const int b    = s >> 4;
  const int hq   = s & 15;                     // h-quad
  const int h0p  = hq * 4;                     // padded-row base

  // ---- zero the w-halo slots (slot 0 and 65 of each of 6 rows) ----
  if (t < 96) {
    const int r = t >> 4, sl = (t >> 3) & 1, j = t & 7;
    reinterpret_cast<int4*>(xs)[r * 528 + sl * 520 + j] = int4{0, 0, 0, 0};
  }

  // ================= PHASE 0: in-block x transpose =================
  // fp32 tile pair overlaid on asw region (33,280 B < 98,304).
  {
    float* ft = reinterpret_cast<float*>(asw);     // [2][64*65]
    const f32x4 z4 = {0.f, 0.f, 0.f, 0.f};
#pragma unroll
    for (int rp = 0; rp < 3; ++rp) {
#pragma unroll
      for (int rr = 0; rr < 2; ++rr) {
        const int r = rp * 2 + rr;
        const int h = h0p + r - 1;                 // interior h, may be OOB
        float* tile = ft + rr * 4160;
        const int c = t >> 3, ws = (t & 7) * 8;
        if ((unsigned)h < 64u) {
          const float* src =
              x + (((size_t)(b * NC + c)) * NH + h) * NW + ws;
          *reinterpret_cast<f32x4*>(tile + c * 65 + ws) =
              *reinterpret_cast<const f32x4*>(src);
          *reinterpret_cast<f32x4*>(tile + c * 65 + ws + 4) =
              *reinterpret_cast<const f32x4*>(src + 4);
        } else {
          *reinterpret_cast<f32x4*>(tile + c * 65 + ws) = z4;
          *reinterpret_cast<f32x4*>(tile + c * 65 + ws + 4) = z4;
        }
      }
      __syncthreads();
#pragma unroll
      for (int rr = 0; rr < 2; ++rr) {
        const int r = rp * 2 + rr;
        const float* tile = ft + rr * 4160;
        const int w2 = t >> 3, cb = t & 7;
        uint32_t dd[4];
#pragma unroll
        for (int j = 0; j < 4; ++j)
          dd[j] = pk2(tile[(cb * 8 + 2 * j) * 65 + w2],
                      tile[(cb * 8 + 2 * j + 1) * 65 + w2]);
        reinterpret_cast<int4*>(xs)[r * 528 + 8 + w2 * 8 + (cb ^ (w2 & 7))] =
            int4{(int)dd[0], (int)dd[1], (int)dd[2], (int)dd[3]};
      }
      __syncthreads();
    }
  }

  // ---- as staging: group g = taps p = dh*3 + g (dh 0..2), all 256 d ----
  auto stage_a = [&](int g) {
#pragma unroll
    for (int j = 0; j < 12; ++j) {
      const int ch = wid * 12 + j;             // 0..95
      const int tap = ch >> 5, k = ch & 31;    // 32 chunks per tap
      gld16(Wd + (size_t)(tap * 3 + g) * 16384 + k * 512 + lane * 8,
            asw + tap * 16384 + k * 512);
    }
  };
  stage_a(0);

  const int wd  = wid & 3;      // d-tile (64 each)
  const int wn  = wid >> 2;     // pix half (128 each = 2 h-rows)
  const int l15 = lane & 15;
  const int lg  = lane >> 4;

  f32x4 acc[8][4];              // [pix-frag][d-frag]
#pragma unroll
  for (int pb = 0; pb < 8; ++pb)
#pragma unroll
    for (int db = 0; db < 4; ++db)
      acc[pb][db] = (f32x4){0.f, 0.f, 0.f, 0.f};

  __syncthreads();              // xs + as(g0) resident

  // ================= PHASE 1: S = conv(x, dict) =================
#pragma unroll
  for (int g = 0; g < 3; ++g) {
    const int dw = g - 1;
#pragma unroll
    for (int q = 0; q < 2; ++q) {
      const int cbB = (q * 4 + lg) ^ ((l15 + dw) & 7);
      const uint16_t* xb = xs + (l15 + dw + 1) * 64 + cbB * 8;
      bf16x8 braw[4][4];        // rows wn*2+rr, shared across 3 dh taps
#pragma unroll
      for (int rr = 0; rr < 4; ++rr)
#pragma unroll
        for (int nw = 0; nw < 4; ++nw)
          braw[rr][nw] = __builtin_bit_cast(bf16x8,
              *reinterpret_cast<const s16x8*>(
                  xb + (wn * 2 + rr) * 4224 + nw * 1024));
      const int cbA = (q * 4 + lg) ^ (l15 & 7);
      const uint16_t* ab = asw + (wd * 64 + l15) * 64 + cbA * 8;
#pragma unroll
      for (int dh = 0; dh < 3; ++dh) {
        bf16x8 af[4];
#pragma unroll
        for (int db = 0; db < 4; ++db)
          af[db] = __builtin_bit_cast(bf16x8,
              *reinterpret_cast<const s16x8*>(
                  ab + dh * 16384 + db * 1024));
#pragma unroll
        for (int pb = 0; pb < 8; ++pb)
#pragma unroll
          for (int db = 0; db < 4; ++db)
            acc[pb][db] = __builtin_amdgcn_mfma_f32_16x16x32_bf16(
                braw[(pb >> 2) + dh][pb & 3], af[db], acc[pb][db], 0, 0, 0);
      }
    }
    if (g < 2) {
      __syncthreads();          // all waves done reading as(g)
      stage_a(g + 1);
      __syncthreads();          // as(g+1) resident
    }
  }

  // ---- acc -> S (bf16, XOR-swizzled rows); overlays xs/as ----
  __syncthreads();              // all phase-1 LDS reads complete
#pragma unroll
  for (int pb = 0; pb < 8; ++pb) {
#pragma unroll
    for (int db = 0; db < 4; ++db) {
      const int d   = wd * 64 + db * 16 + l15;
      const int pix = (wn * 2 + (pb >> 2)) * 64 + (pb & 3) * 16 + lg * 4;
      u32x2 u;
      u[0] = pk2(acc[pb][db][0], acc[pb][db][1]);
      u[1] = pk2(acc[pb][db][2], acc[pb][db][3]);
      *reinterpret_cast<u32x2*>(
          Sb + d * 512 + ((pix * 2) ^ ((d & 7) << 4))) = u;
    }
  }
  __syncthreads();              // S fully resident

  // ================= PHASE 2: gather-combine =================
  const int hrow = lane >> 4;          // 0..3 within quad
  const int wcol = (lane & 15) * 4;    // 4 consecutive w per lane
#pragma unroll 4
  for (int oo = 0; oo < 64; ++oo) {
    const int o = wid * 64 + oo;
    const int4 iv = *reinterpret_cast<const int4*>(idx + o * 4);
    const f32x4 cv = *reinterpret_cast<const f32x4*>(coef + o * 4);
    const float bv = bias[o];
    f32x4 v = {bv, bv, bv, bv};
#define GATH(ROW, CS) do {                                                  \
      const int r_ = (ROW);                                                 \
      const u32x2 u_ = *reinterpret_cast<const u32x2*>(                     \
          Sb + r_ * 512 + ((lane * 8) ^ ((r_ & 7) << 4)));                  \
      const float c_ = (CS);                                                \
      v[0] += c_ * ubf_lo(u_[0]);  v[1] += c_ * ubf_hi(u_[0]);              \
      v[2] += c_ * ubf_lo(u_[1]);  v[3] += c_ * ubf_hi(u_[1]);              \
    } while (0)
    GATH(iv.x, cv[0]);
    GATH(iv.y, cv[1]);
    GATH(iv.z, cv[2]);
    GATH(iv.w, cv[3]);
#undef GATH
    float* dst = out + ((size_t)(b * NO + o) * NH + hq * 4 + hrow) * NW + wcol;
    __builtin_nontemporal_store(v, reinterpret_cast<f32x4*>(dst));
  }
}

extern "C" void kernel_launch(void* const* d_in, const int* in_sizes, int n_in,
                              void* d_out, int out_size, void* d_ws, size_t ws_size,
                              hipStream_t stream) {
  const float* x    = (const float*)d_in[0];
  const float* dict = (const float*)d_in[1];
  const float* coef = (const float*)d_in[2];
  const float* bias = (const float*)d_in[3];
  const int*   idx  = (const int*)d_in[4];
  float* out = (float*)d_out;

  // workspace: Wd 288 KiB at 0 (xh intermediate eliminated)
  uint16_t* Wd = (uint16_t*)d_ws;

  hipLaunchKernelGGL(k_prep_wd, dim3(ND), dim3(256), 0, stream, dict, Wd);
  hipLaunchKernelGGL(k_conv, dim3(512), dim3(512), 0, stream,
                     x, Wd, coef, idx, bias, out);
}